// Round 6
// baseline (258.306 us; speedup 1.0000x reference)
//
#include <hip/hip_runtime.h>

#define NFR   4
#define NLOCC 2048
#define NNEIN 64
#define EMB   128
#define PDIM  64
#define NH    8
#define LNEPS 1e-5f
#define NROW  (NFR*NLOCC)   // 8192

// workspace layout (float offsets)
#define WS_Q   0
#define WS_K   (NROW*EMB)        // 1,048,576
#define WS_FV  (2*NROW*EMB)      // 2,097,152 : fv[row][8]

__device__ __forceinline__ void fma4(float4& acc, const float4 a, const float4 b) {
    acc.x = fmaf(a.x, b.x, acc.x);
    acc.y = fmaf(a.y, b.y, acc.y);
    acc.z = fmaf(a.z, b.z, acc.z);
    acc.w = fmaf(a.w, b.w, acc.w);
}
__device__ __forceinline__ void fma4s(float4& acc, const float s, const float4 b) {
    acc.x = fmaf(s, b.x, acc.x);
    acc.y = fmaf(s, b.y, acc.y);
    acc.z = fmaf(s, b.z, acc.z);
    acc.w = fmaf(s, b.w, acc.w);
}
__device__ __forceinline__ float hsum4(const float4 a) {
    return (a.x + a.y) + (a.z + a.w);
}
__device__ __forceinline__ float dot4(const float4 a, const float4 b) {
    return fmaf(a.x, b.x, fmaf(a.y, b.y, fmaf(a.z, b.z, a.w * b.w)));
}
__device__ __forceinline__ float4 scale4(const float4 a, const float s) {
    return make_float4(a.x*s, a.y*s, a.z*s, a.w*s);
}

// ---------------- Kernel 1: LN(query) + q,k projections + fv (unchanged) ----------------
__global__ __launch_bounds__(256, 2) void qkfv_kernel(
    const float* __restrict__ query,
    const float* __restrict__ ln_g, const float* __restrict__ ln_b,
    const float* __restrict__ Wq, const float* __restrict__ Wk,
    const float* __restrict__ Wv, const float* __restrict__ Wforce,
    float* __restrict__ ws)
{
    __shared__ float  gb_s[2][EMB];
    __shared__ float  qn_s[16*132];
    __shared__ float  wt_s[2][16*132];
    __shared__ float4 wvf_s4[8*33];      // Wv_f[h][ch], padded rows (33 float4)
    const int t = threadIdx.x;
    const int rowbase = blockIdx.x * 16;

    if (t < 64) {
        const float* src = (t < 32) ? ln_g : ln_b;
        ((float4*)gb_s[t >> 5])[t & 31] = ((const float4*)src)[t & 31];
    }

    // Wv_f[h][e] = sum_d Wforce[h*16+d] * Wv[h*16+d][e]
    {
        const int h = t >> 5, ch = t & 31;
        float4 acc = make_float4(0.f, 0.f, 0.f, 0.f);
        #pragma unroll
        for (int d = 0; d < 16; ++d) {
            const float wf = Wforce[h*16 + d];
            const float4 wv = ((const float4*)(Wv + (size_t)(h*16 + d)*EMB))[ch];
            fma4s(acc, wf, wv);
        }
        wvf_s4[h*33 + ch] = acc;
    }

    // LayerNorm: 16 threads per row, 8 floats each
    const int r   = t >> 4;
    const int seg = t & 15;
    float4 x0 = ((const float4*)query)[(size_t)(rowbase + r)*32 + seg*2 + 0];
    float4 x1 = ((const float4*)query)[(size_t)(rowbase + r)*32 + seg*2 + 1];
    float s  = (x0.x + x0.y) + (x0.z + x0.w) + (x1.x + x1.y) + (x1.z + x1.w);
    float ss = x0.x*x0.x + x0.y*x0.y + x0.z*x0.z + x0.w*x0.w
             + x1.x*x1.x + x1.y*x1.y + x1.z*x1.z + x1.w*x1.w;
    #pragma unroll
    for (int m = 1; m < 16; m <<= 1) {
        s  += __shfl_xor(s,  m, 64);
        ss += __shfl_xor(ss, m, 64);
    }
    const float mean = s * (1.0f / 128.0f);
    const float var  = ss * (1.0f / 128.0f) - mean * mean;
    const float rstd = rsqrtf(var + LNEPS);
    __syncthreads();   // gb_s + wvf_s4 ready

    {
        const int c0 = seg * 8;
        float4 o0, o1;
        o0.x = (x0.x - mean)*rstd*gb_s[0][c0+0] + gb_s[1][c0+0];
        o0.y = (x0.y - mean)*rstd*gb_s[0][c0+1] + gb_s[1][c0+1];
        o0.z = (x0.z - mean)*rstd*gb_s[0][c0+2] + gb_s[1][c0+2];
        o0.w = (x0.w - mean)*rstd*gb_s[0][c0+3] + gb_s[1][c0+3];
        o1.x = (x1.x - mean)*rstd*gb_s[0][c0+4] + gb_s[1][c0+4];
        o1.y = (x1.y - mean)*rstd*gb_s[0][c0+5] + gb_s[1][c0+5];
        o1.z = (x1.z - mean)*rstd*gb_s[0][c0+6] + gb_s[1][c0+6];
        o1.w = (x1.w - mean)*rstd*gb_s[0][c0+7] + gb_s[1][c0+7];
        ((float4*)qn_s)[r*33 + seg*2 + 0] = o0;
        ((float4*)qn_s)[r*33 + seg*2 + 1] = o1;
    }
    __syncthreads();

    const int rp = t >> 5;
    const int r0 = rp * 2;
    const int cq = t & 31;
    const int sc0 = t >> 2;
    const int si0 = t & 3;
    const float4* qn4 = (const float4*)qn_s;

    for (int w = 0; w < 2; ++w) {
        const float4* W4 = (const float4*)((w == 0) ? Wq : Wk);
        float4 acc0 = make_float4(0.f,0.f,0.f,0.f);
        float4 acc1 = make_float4(0.f,0.f,0.f,0.f);
        {
            float4 g0 = W4[(size_t)sc0*32 + si0];
            float4 g1 = W4[(size_t)(sc0+64)*32 + si0];
            float* wt = wt_s[0];
            wt[(si0*4+0)*132 + sc0] = g0.x; wt[(si0*4+1)*132 + sc0] = g0.y;
            wt[(si0*4+2)*132 + sc0] = g0.z; wt[(si0*4+3)*132 + sc0] = g0.w;
            wt[(si0*4+0)*132 + sc0+64] = g1.x; wt[(si0*4+1)*132 + sc0+64] = g1.y;
            wt[(si0*4+2)*132 + sc0+64] = g1.z; wt[(si0*4+3)*132 + sc0+64] = g1.w;
        }
        __syncthreads();
        #pragma unroll
        for (int tau = 0; tau < 8; ++tau) {
            const int buf = tau & 1;
            float4 ng0, ng1;
            if (tau < 7) {
                ng0 = W4[(size_t)sc0*32 + (tau+1)*4 + si0];
                ng1 = W4[(size_t)(sc0+64)*32 + (tau+1)*4 + si0];
            }
            const float4* wt4 = (const float4*)wt_s[buf];
            #pragma unroll
            for (int e4 = 0; e4 < 4; ++e4) {
                float4 a0 = qn4[r0*33 + tau*4 + e4];
                float4 a1 = qn4[(r0+1)*33 + tau*4 + e4];
                const float* a0p = (const float*)&a0;
                const float* a1p = (const float*)&a1;
                #pragma unroll
                for (int ee = 0; ee < 4; ++ee) {
                    const float4 wv = wt4[(e4*4+ee)*33 + cq];
                    fma4s(acc0, a0p[ee], wv);
                    fma4s(acc1, a1p[ee], wv);
                }
            }
            if (tau < 7) {
                float* wt = wt_s[buf ^ 1];
                wt[(si0*4+0)*132 + sc0] = ng0.x; wt[(si0*4+1)*132 + sc0] = ng0.y;
                wt[(si0*4+2)*132 + sc0] = ng0.z; wt[(si0*4+3)*132 + sc0] = ng0.w;
                wt[(si0*4+0)*132 + sc0+64] = ng1.x; wt[(si0*4+1)*132 + sc0+64] = ng1.y;
                wt[(si0*4+2)*132 + sc0+64] = ng1.z; wt[(si0*4+3)*132 + sc0+64] = ng1.w;
            }
            __syncthreads();
        }
        const float sc = (w == 0) ? 0.25f : 1.0f;   // HD^-0.5 folded into q
        float4* dst = (float4*)(ws + (w == 0 ? WS_Q : WS_K));
        dst[(size_t)(rowbase + r0)*32 + cq]     = scale4(acc0, sc);
        dst[(size_t)(rowbase + r0 + 1)*32 + cq] = scale4(acc1, sc);
    }

    if (t < 128) {
        const int rr = t >> 3, h = t & 7;
        float4 acc = make_float4(0.f,0.f,0.f,0.f);
        #pragma unroll
        for (int ch = 0; ch < 32; ++ch)
            fma4(acc, qn4[rr*33 + ch], wvf_s4[h*33 + ch]);
        ws[WS_FV + (size_t)(rowbase + rr)*NH + h] = hsum4(acc);
    }
}

// ---------------- Kernel 2: attn + force, 2 compute barriers ----------------
// 8192 blocks x 256 threads. Per-wave G/SG/C LDS copies make the QK->bias chain
// intra-wave (no barrier). pair in registers (direct n-mapped load). Softmax+
// PV+force fused. LDS ~14 KB.
__global__ __launch_bounds__(256, 6) void attn_force_kernel(
    const float* __restrict__ pair, const int* __restrict__ nlist,
    const float* __restrict__ delta_pos, const float* __restrict__ attn_mask,
    const float* __restrict__ pn_g, const float* __restrict__ pn_b,
    const float* __restrict__ Wbias, const float* __restrict__ bbias,
    const float* __restrict__ ws, float* __restrict__ out)
{
    __shared__ float  logit_s[NNEIN*9];   // [n][9] stride coprime with 32
    __shared__ float4 G_s4[4][128];       // per-wave copy of G[8][64] head-major
    __shared__ float  csg_s[4][16];       // per-wave SG[0..7], C[8..15]
    __shared__ float  fv_s[NNEIN*9];      // fv gathered, [n][9]
    __shared__ float  dp_s[192];          // delta_pos rows
    __shared__ float  fpart[4][3];

    const int t    = threadIdx.x;
    const int bid  = blockIdx.x;
    const int fr   = bid >> 11;
    const int l    = bid & 2047;
    const int w    = t >> 6;
    const int lane = t & 63;
    const int half = lane >> 5;        // gather mapping
    const int c    = lane & 31;        // k chunk index
    const int n    = t >> 2;           // n-mapping neighbor (= w*16 + lane>>2)
    const int sub  = t & 3;
    const int h0   = sub * 2, h1 = h0 + 1;
    const int i32  = lane & 31;        // softmax row index
    const int hh   = t >> 5;           // softmax head

    // ---------------- independent loads (registers) ----------------
    // pair: direct n-mapped (64B/lane-group; TA has headroom, saves LDS round-trip)
    const float4* prow = (const float4*)(pair + ((size_t)bid*NNEIN + n)*PDIM);
    float4 pr0 = prow[sub*4 + 0];
    float4 pr1 = prow[sub*4 + 1];
    float4 pr2 = prow[sub*4 + 2];
    float4 pr3 = prow[sub*4 + 3];

    const int jv = nlist[(size_t)bid*NNEIN + lane];   // every wave holds full nlist
    const float4 q4c = ((const float4*)(ws + WS_Q))[(size_t)bid*32 + c];

    const float mask0 = attn_mask[((size_t)(fr*NH + h0)*NLOCC + l)*NNEIN + n];
    const float mask1 = attn_mask[((size_t)(fr*NH + h1)*NLOCC + l)*NNEIN + n];

    // ---------------- per-wave parameter staging (intra-wave use, no barrier) ----
    {
        // G[h][p] = pn_g[p]*Wbias[h][p] : 2 float4 entries per lane
        const float4* wb4 = (const float4*)Wbias;
        const float4* pg4 = (const float4*)pn_g;
        #pragma unroll
        for (int i = 0; i < 2; ++i) {
            const int idx = i*64 + lane;          // 0..127
            const float4 wb = wb4[idx];
            const float4 pg = pg4[idx & 15];
            G_s4[w][idx] = make_float4(wb.x*pg.x, wb.y*pg.y, wb.z*pg.z, wb.w*pg.w);
        }
        // SG[h], C[h]: 8-lane groups (h = lane>>3, s8 = lane&7)
        const int h8 = lane >> 3, s8 = lane & 7;
        const float4 wba = wb4[h8*16 + s8*2 + 0];
        const float4 wbb = wb4[h8*16 + s8*2 + 1];
        const float4 pga = pg4[s8*2 + 0];
        const float4 pgb = pg4[s8*2 + 1];
        const float4 pba = ((const float4*)pn_b)[s8*2 + 0];
        const float4 pbb = ((const float4*)pn_b)[s8*2 + 1];
        float sg = dot4(wba, pga) + dot4(wbb, pgb);
        float cb = dot4(wba, pba) + dot4(wbb, pbb);
        sg += __shfl_xor(sg, 1, 64); sg += __shfl_xor(sg, 2, 64); sg += __shfl_xor(sg, 4, 64);
        cb += __shfl_xor(cb, 1, 64); cb += __shfl_xor(cb, 2, 64); cb += __shfl_xor(cb, 4, 64);
        if (s8 == 0) {
            csg_s[w][h8]     = sg;
            csg_s[w][8 + h8] = cb + bbias[h8];
        }
    }
    // dp staging (read after barrier 1)
    if (t >= 192 && t < 240)
        ((float4*)dp_s)[t - 192] = ((const float4*)(delta_pos + (size_t)bid*192))[t - 192];

    // fv: float2 per (n,sub); stage n-mapped (read cross-wave after barrier 1)
    {
        const int    jn  = __shfl(jv, n & 63, 64);
        const float2 fv2 = ((const float2*)(ws + WS_FV + ((size_t)(fr << 11) + jn)*NH))[sub];
        fv_s[n*9 + h0] = fv2.x;
        fv_s[n*9 + h1] = fv2.y;
    }

    // ---------------- QK gather + raw logits (gather mapping, intra-wave n-range) ----
    {
        const float4* k4 = (const float4*)(ws + WS_K) + (size_t)(fr << 11)*32;
        int jr[8];
        #pragma unroll
        for (int i = 0; i < 8; ++i)
            jr[i] = __shfl(jv, (w << 4) | (i << 1) | half, 64);
        float4 kkA[4], kkB[4];
        #pragma unroll
        for (int i = 0; i < 4; ++i) kkA[i] = k4[(size_t)jr[i]*32 + c];
        #pragma unroll
        for (int i = 0; i < 4; ++i) kkB[i] = k4[(size_t)jr[4+i]*32 + c];
        float p[8];
        #pragma unroll
        for (int i = 0; i < 4; ++i) p[i]     = dot4(kkA[i], q4c);
        #pragma unroll
        for (int i = 0; i < 4; ++i) p[4 + i] = dot4(kkB[i], q4c);
        #pragma unroll
        for (int i = 0; i < 8; ++i) {
            float pp = p[i];
            pp += __shfl_xor(pp, 1, 64);
            pp += __shfl_xor(pp, 2, 64);
            if ((c & 3) == 0)
                logit_s[((w << 4) | (i << 1) | half)*9 + (c >> 2)] = pp;
        }
    }
    // NO barrier: wave w wrote logits for n in [16w,16w+16) and now RMWs the same.

    // ---------------- pair LN + bias, RMW into logits (n-mapping, intra-wave) ----
    {
        float s  = hsum4(pr0) + hsum4(pr1) + hsum4(pr2) + hsum4(pr3);
        float ss = dot4(pr0, pr0) + dot4(pr1, pr1) + dot4(pr2, pr2) + dot4(pr3, pr3);
        s  += __shfl_xor(s, 1, 64);  s  += __shfl_xor(s, 2, 64);
        ss += __shfl_xor(ss, 1, 64); ss += __shfl_xor(ss, 2, 64);
        const float mean = s * (1.0f / 64.0f);
        const float var  = ss * (1.0f / 64.0f) - mean * mean;
        const float rstd = rsqrtf(var + LNEPS);

        float d[NH];
        #pragma unroll
        for (int h = 0; h < NH; ++h) d[h] = 0.f;
        const float4 prq[4] = {pr0, pr1, pr2, pr3};
        #pragma unroll
        for (int q = 0; q < 4; ++q) {
            #pragma unroll
            for (int h = 0; h < NH; ++h)
                d[h] += dot4(prq[q], G_s4[w][h*16 + sub*4 + q]);
        }
        #pragma unroll
        for (int h = 0; h < NH; ++h) {
            d[h] += __shfl_xor(d[h], 1, 64);
            d[h] += __shfl_xor(d[h], 2, 64);
        }
        logit_s[n*9 + h0] += rstd*(d[h0] - mean*csg_s[w][h0]) + csg_s[w][8 + h0] + mask0;
        logit_s[n*9 + h1] += rstd*(d[h1] - mean*csg_s[w][h1]) + csg_s[w][8 + h1] + mask1;
    }
    __syncthreads();   // (1) logits complete, fv/dp staged

    // ---------------- softmax + PV + force (fused, hh/i32 mapping) ----------------
    {
        const float a = logit_s[i32*9 + hh], b = logit_s[(i32 + 32)*9 + hh];
        float m = fmaxf(a, b);
        #pragma unroll
        for (int mm = 16; mm >= 1; mm >>= 1) m = fmaxf(m, __shfl_xor(m, mm, 64));
        const float ea = __expf(a - m), eb = __expf(b - m);
        float sum = ea + eb;
        #pragma unroll
        for (int mm = 16; mm >= 1; mm >>= 1) sum += __shfl_xor(sum, mm, 64);
        const float inv = 1.0f / sum;
        float ca = ea * inv * fv_s[i32*9 + hh];
        float cb = eb * inv * fv_s[(i32 + 32)*9 + hh];
        ca += __shfl_xor(ca, 32, 64);   // + the wave's other head
        cb += __shfl_xor(cb, 32, 64);
        const float dpax = dp_s[i32*3 + 0],      dpay = dp_s[i32*3 + 1],      dpaz = dp_s[i32*3 + 2];
        const float dpbx = dp_s[(i32+32)*3 + 0], dpby = dp_s[(i32+32)*3 + 1], dpbz = dp_s[(i32+32)*3 + 2];
        float f0 = ca*dpax + cb*dpbx;
        float f1 = ca*dpay + cb*dpby;
        float f2 = ca*dpaz + cb*dpbz;
        #pragma unroll
        for (int mm = 1; mm <= 16; mm <<= 1) {
            f0 += __shfl_xor(f0, mm, 64);
            f1 += __shfl_xor(f1, mm, 64);
            f2 += __shfl_xor(f2, mm, 64);
        }
        if (lane == 0) {
            fpart[w][0] = f0; fpart[w][1] = f1; fpart[w][2] = f2;
        }
    }
    __syncthreads();   // (2)

    if (t < 3)
        out[(size_t)bid*3 + t] = fpart[0][t] + fpart[1][t] + fpart[2][t] + fpart[3][t];
}

extern "C" void kernel_launch(void* const* d_in, const int* in_sizes, int n_in,
                              void* d_out, int out_size, void* d_ws, size_t ws_size,
                              hipStream_t stream) {
    const float* query     = (const float*)d_in[0];
    const float* pair      = (const float*)d_in[1];
    const int*   nlist     = (const int*)d_in[2];
    const float* delta_pos = (const float*)d_in[3];
    const float* attn_mask = (const float*)d_in[4];
    const float* ln_g      = (const float*)d_in[5];
    const float* ln_b      = (const float*)d_in[6];
    const float* pn_g      = (const float*)d_in[7];
    const float* pn_b      = (const float*)d_in[8];
    const float* Wq        = (const float*)d_in[9];
    const float* Wk        = (const float*)d_in[10];
    const float* Wv        = (const float*)d_in[11];
    const float* Wbias     = (const float*)d_in[12];
    const float* bbias     = (const float*)d_in[13];
    const float* Wforce    = (const float*)d_in[14];
    float* out = (float*)d_out;
    float* ws  = (float*)d_ws;

    qkfv_kernel<<<512, 256, 0, stream>>>(query, ln_g, ln_b, Wq, Wk, Wv, Wforce, ws);
    attn_force_kernel<<<NROW, 256, 0, stream>>>(pair, nlist, delta_pos, attn_mask,
                                                pn_g, pn_b, Wbias, bbias, ws, out);
}